// Round 23
// baseline (125.762 us; speedup 1.0000x reference)
//
#include <hip/hip_runtime.h>
#include <hip/hip_bf16.h>
#include <stdint.h>

#define T_DIM 2048
#define N_DIM 512
#define DV_DIM 128
#define NH 16          // B*H

typedef __bf16 bf16x8 __attribute__((ext_vector_type(8)));
typedef float f32x4 __attribute__((ext_vector_type(4)));
typedef float f32x2 __attribute__((ext_vector_type(2)));
typedef unsigned int u32x2 __attribute__((ext_vector_type(2)));
typedef unsigned int u32x4 __attribute__((ext_vector_type(4)));

__device__ __forceinline__ unsigned bf16rne(float x) {
  unsigned u = __builtin_bit_cast(unsigned, x);
  return (u + 0x7FFFu + ((u >> 16) & 1u)) >> 16;
}

__device__ __forceinline__ void load_lds16(const void* g, void* l) {
  __builtin_amdgcn_global_load_lds((const __attribute__((address_space(1))) void*)g,
                                   (__attribute__((address_space(3))) void*)l, 16, 0, 0);
}

// ---------------- fused prep: RoPE (blocks 0..4095, no transpose) and
// V frag-linear transform (blocks 4096..5119), one launch ----------------
// qrT eliminated (hprefix now transposes in-LDS from qr): prep traffic drops
// 219 -> 186 MB. All outputs bh-pinned to XCD bh%8.
__global__ __launch_bounds__(256, 2)
void prep_kernel(const float* __restrict__ Q, const float* __restrict__ freqs,
                 const float* __restrict__ V,
                 unsigned int* __restrict__ qrOut,
                 unsigned short* __restrict__ vt32) {
  __shared__ unsigned int smem32[2112];      // used by V path only
  const int bid = blockIdx.x;
  const int tid = threadIdx.x;

  if (bid < 4096) {
    // ---- RoPE: Q fp32 [bh][t][n] -> qr bf16 [bh][t][n] ----
    const int k = bid >> 3;
    const int bh = (bid & 7) + 8 * (k & 1);
    const int rest = k >> 1;           // 0..255
    const int tt = rest >> 3;          // 0..31
    const int nn = rest & 7;           // 0..7
    const int t0 = tt * 64, n0 = nn * 64;

    const int c2 = tid & 31;           // n-pair, invariant across iters
    const int r0 = tid >> 5;           // 0..7
    const float f = freqs[n0 + 2 * c2];

    const float* src = Q + ((size_t)bh * T_DIM + t0) * N_DIM + n0 + 2 * c2;
    f32x2 qv[8];
#pragma unroll
    for (int it = 0; it < 8; ++it)
      qv[it] = *(const f32x2*)(src + (size_t)(it * 8 + r0) * N_DIM);

    unsigned int* qrb = qrOut + ((size_t)bh * T_DIM + t0) * 256 + (n0 >> 1) + c2;
#pragma unroll
    for (int it = 0; it < 8; ++it) {
      int r = it * 8 + r0;             // t-local
      float ph = (float)(t0 + r) * f;
      ph = ph - floorf(ph);            // revolutions in [0,1)
      float sn = __builtin_amdgcn_sinf(ph);
      float cn = __builtin_amdgcn_cosf(ph);
      unsigned lo = bf16rne(qv[it].x * cn - qv[it].y * sn);
      unsigned hi = bf16rne(qv[it].y * cn + qv[it].x * sn);
      qrb[(size_t)r * 256] = lo | (hi << 16);
    }
  } else {
    // ---- V fp32 [bh][t][d] -> frag-linear bf16 (16x16x32 B-frag):
    // vt[bh][sblk32][slot=df*64+lane][i] = V[s0+8*(lane>>4)+i][16*df+(lane&15)]
    auto tile = reinterpret_cast<unsigned short(*)[128]>(smem32);
    const int vb = bid - 4096;
    const int bh = (vb & 7) + 8 * ((vb >> 3) & 1);
    const int sb = vb >> 4;            // 0..63
    const float* src = V + ((size_t)bh * T_DIM + sb * 32) * DV_DIM;
    f32x4 vv[4];
#pragma unroll
    for (int i = 0; i < 4; ++i)
      vv[i] = *(const f32x4*)(src + (size_t)(i * 1024 + tid * 4));
#pragma unroll
    for (int i = 0; i < 4; ++i) {
      int idx4 = i * 256 + tid;        // vec4-slot over [32][128]
      int row = idx4 >> 5;
      int col4 = idx4 & 31;
      u32x2 pk;
      pk[0] = bf16rne(vv[i][0]) | (bf16rne(vv[i][1]) << 16);
      pk[1] = bf16rne(vv[i][2]) | (bf16rne(vv[i][3]) << 16);
      *(u32x2*)&tile[row][col4 * 4] = pk;
    }
    __syncthreads();
    unsigned short* dst = vt32 + ((size_t)bh * 64 + sb) * 4096;
#pragma unroll
    for (int jj = 0; jj < 2; ++jj) {
      int j = jj * 256 + tid;
      int df = j >> 6, ln = j & 63;
      int lh2 = ln & 15, lg2 = ln >> 4;
      unsigned short tmp[8];
#pragma unroll
      for (int i = 0; i < 8; ++i) tmp[i] = tile[8 * lg2 + i][16 * df + lh2];
      *(u32x4*)(dst + j * 8) = *(u32x4*)tmp;
    }
  }
}

// ---------------- fused G + exclusive prefix -> H ----------------
// H[t] = sum_{chunks k < i} QR_k^T V_k, emitted bf16 B-frag-linear.
// A-operand now transposed IN-LDS from qr (qrT eliminated): per chunk the wg
// stages its 128t x 128n qr tile ([t][n], row stride 136 shorts = 16B-aligned,
// single b128 writes, 2-way banks) and gathers A-frags as ds_read_u16 pairs.
__global__ __launch_bounds__(256, 1)
void hprefix_kernel(const unsigned short* __restrict__ qr,
                    const unsigned short* __restrict__ vt,
                    unsigned short* __restrict__ H) {
  __shared__ unsigned short tlds[128 * 136];   // 34816 B
  const int bid = blockIdx.x;
  const int bh = (bid & 7) + 8 * ((bid >> 3) & 1);
  const int slab = bid >> 4;           // 0..15
  const int nsl = slab >> 2;
  const int dsl = slab & 3;
  const int tid = threadIdx.x;
  const int w = tid >> 6;
  const int lane = tid & 63;
  const int lh = lane & 15, lg = lane >> 4;

  const unsigned short* qr_h = qr + (size_t)bh * (T_DIM * N_DIM);
  const unsigned short* vt_h = vt + (size_t)bh * (64 * 4096);
  unsigned short* H_h = H + (size_t)bh * (16 * 65536);

  const f32x4 fzero = {0.f, 0.f, 0.f, 0.f};
  f32x4 acc00 = fzero, acc01 = fzero, acc10 = fzero, acc11 = fzero;

  const int n0g = w * 32 + lh;         // a0 gather column; a1 = +16

  for (int ch = 0; ch < 16; ++ch) {
    // ---- emit H_ch = prefix so far (exclusive) ----
#pragma unroll
    for (int nf = 0; nf < 2; ++nf)
#pragma unroll
      for (int dfl = 0; dfl < 2; ++dfl) {
        const f32x4 a = (nf == 0) ? (dfl == 0 ? acc00 : acc01)
                                  : (dfl == 0 ? acc10 : acc11);
        int nloc = w * 32 + nf * 16 + 4 * lg;
        int nblk = nsl * 4 + (nloc >> 5);
        int lg2 = (nloc >> 3) & 3;
        int i0 = nloc & 7;
        int df = dsl * 2 + dfl;
        int slot = df * 64 + lg2 * 16 + lh;
        u32x2 pk;
        pk[0] = bf16rne(a[0]) | (bf16rne(a[1]) << 16);
        pk[1] = bf16rne(a[2]) | (bf16rne(a[3]) << 16);
        *(u32x2*)(H_h + (size_t)ch * 65536 + nblk * 4096 + slot * 8 + i0) = pk;
      }
    // ---- stage qr tile: tlds[t][n] = qr[ch*128+t][nsl*128+n] ----
#pragma unroll
    for (int it = 0; it < 8; ++it) {
      int slot = it * 256 + tid;       // 0..2047
      int t = slot >> 4;               // 0..127
      int n8 = slot & 15;              // 16B group
      u32x4 v = *(const u32x4*)(qr_h + (size_t)(ch * 128 + t) * N_DIM + nsl * 128 + n8 * 8);
      *(u32x4*)&tlds[t * 136 + n8 * 8] = v;
    }
    __syncthreads();
    // ---- accumulate G_ch (A gathered transposed from tlds) ----
#pragma unroll
    for (int ks = 0; ks < 4; ++ks) {
      const int tcol = ks * 32 + lg * 8;
      const int gb = tcol * 136 + n0g;
      u32x4 A0, A1;
#pragma unroll
      for (int p = 0; p < 4; ++p) {
        A0[p] = (unsigned)tlds[gb + (2 * p) * 136]
              | ((unsigned)tlds[gb + (2 * p + 1) * 136] << 16);
        A1[p] = (unsigned)tlds[gb + (2 * p) * 136 + 16]
              | ((unsigned)tlds[gb + (2 * p + 1) * 136 + 16] << 16);
      }
      u32x4 b0, b1;
      {
        const unsigned short* pb = vt_h + (size_t)(ch * 4 + ks) * 4096
                                   + ((dsl * 2) * 64 + lane) * 8;
        b0 = *(const u32x4*)pb;
        b1 = *(const u32x4*)(pb + 512);
      }
      acc00 = __builtin_amdgcn_mfma_f32_16x16x32_bf16(__builtin_bit_cast(bf16x8, A0), __builtin_bit_cast(bf16x8, b0), acc00, 0, 0, 0);
      acc01 = __builtin_amdgcn_mfma_f32_16x16x32_bf16(__builtin_bit_cast(bf16x8, A0), __builtin_bit_cast(bf16x8, b1), acc01, 0, 0, 0);
      acc10 = __builtin_amdgcn_mfma_f32_16x16x32_bf16(__builtin_bit_cast(bf16x8, A1), __builtin_bit_cast(bf16x8, b0), acc10, 0, 0, 0);
      acc11 = __builtin_amdgcn_mfma_f32_16x16x32_bf16(__builtin_bit_cast(bf16x8, A1), __builtin_bit_cast(bf16x8, b1), acc11, 0, 0, 0);
    }
    __syncthreads();   // gathers done before next chunk's restage
  }
}

// ---------------- per-chunk output: O = QR_i H_i + tril(QR_i QR_i^T,-1) V_i ----------------
// (byte-identical to v20/v22's passing version)
__global__ __launch_bounds__(512, 1)
void chunk_kernel(const unsigned short* __restrict__ qr,
                  const unsigned short* __restrict__ vt,
                  const unsigned short* __restrict__ H,
                  float* __restrict__ out) {
  __shared__ unsigned short kh_lds[2][16384];  // 2x32KB: K dbuf, then H dbuf
  __shared__ unsigned short p_lds[8 * 2048];   // 32KB: [wave][sb 4][A-frag 512]

  const int tid = threadIdx.x;
  const int w = tid >> 6;              // 0..7
  const int lane = tid & 63;
  const int lh = lane & 15, lg = lane >> 4;

  const int bid = blockIdx.x;          // 256 wgs
  const int head = (bid & 7) + 8 * ((bid >> 3) & 1);
  const int ch = bid >> 4;             // 0..15

  const unsigned short* qr_h = qr + (size_t)head * (T_DIM * N_DIM);
  const unsigned short* vt_h = vt + (size_t)head * (64 * 4096);
  const unsigned short* H_c = H + ((size_t)head * 16 + ch) * 65536;
  float* out_h = out + (size_t)head * (T_DIM * DV_DIM);

  const int tq = w * 16;               // t local to chunk
  const int tb = ch * 128 + tq;
  const int nsb = (w >> 1) + 1;        // causal 32-s blocks for this wave

  // ---- Q fragments first (tracked): row = t = tb+lh, k = 32ks+8lg+i ----
  u32x4 qf[16];
  {
    const unsigned short* pq = qr_h + (size_t)(tb + lh) * N_DIM + lg * 8;
#pragma unroll
    for (int ks = 0; ks < 16; ++ks) qf[ks] = *(const u32x4*)(pq + ks * 32);
  }

  // K stage: 32-row block sb -> A-frag-linear [f=st*16+ks][lane*8], 32KB
  int koff[4];
#pragma unroll
  for (int it = 0; it < 4; ++it) {
    int j = it * 512 + tid;            // slot 0..2047
    int f = j >> 6, l = j & 63;
    int st = f >> 4, ks = f & 15;
    koff[it] = (st * 16 + (l & 15)) * 1024 + ks * 64 + (l >> 4) * 16;
  }
  auto stageK = [&](int sb, int buf) {
    const char* kb = (const char*)qr_h + ((size_t)ch * 128 + sb * 32) * 1024;
#pragma unroll
    for (int it = 0; it < 4; ++it)
      load_lds16(kb + koff[it], (char*)&kh_lds[buf][0] + (it * 512 + tid) * 16);
  };
  // H stage q (df-pair 2q,2q+1): [nb 16][dfp 2][lane][8] = 32KB
  auto stageH = [&](int q, int buf) {
#pragma unroll
    for (int it = 0; it < 4; ++it) {
      int s = it * 512 + tid;          // slot 0..2047
      int nb = s >> 7;
      int dfp = (s >> 6) & 1;
      int l = s & 63;
      const unsigned short* src = H_c + nb * 4096 + (2 * q + dfp) * 512 + l * 8;
      load_lds16(src, (char*)&kh_lds[buf][0] + s * 16);
    }
  };

  stageK(0, 0);
  stageK(1, 1);

  const f32x4 fzero = {0.f, 0.f, 0.f, 0.f};
  f32x4 o[8];
#pragma unroll
  for (int df = 0; df < 8; ++df) o[df] = fzero;

  // ---- QK loop: 4 staged iterations, counted vmcnt, uniform barriers ----
  for (int sb = 0; sb < 4; ++sb) {
    asm volatile("s_waitcnt vmcnt(4)" ::: "memory");  // K(sb) landed
    __builtin_amdgcn_s_barrier();
    __builtin_amdgcn_sched_barrier(0);

    if (sb < nsb) {
      f32x4 sA = fzero, sB = fzero;
      const unsigned short* kbuf = &kh_lds[sb & 1][0];
#pragma unroll
      for (int ks = 0; ks < 16; ++ks) {
        bf16x8 kf0 = *(const bf16x8*)(kbuf + ks * 512 + lane * 8);
        bf16x8 kf1 = *(const bf16x8*)(kbuf + (16 + ks) * 512 + lane * 8);
        bf16x8 qb = __builtin_bit_cast(bf16x8, qf[ks]);
        sA = __builtin_amdgcn_mfma_f32_16x16x32_bf16(kf0, qb, sA, 0, 0, 0);
        sB = __builtin_amdgcn_mfma_f32_16x16x32_bf16(kf1, qb, sB, 0, 0, 0);
      }
      const int tloc = tq + lh;
#pragma unroll
      for (int r = 0; r < 4; ++r) {
        if (sb * 32 + 4 * lg + r >= tloc) sA[r] = 0.f;
        if (sb * 32 + 16 + 4 * lg + r >= tloc) sB[r] = 0.f;
      }
      u32x2 pkA, pkB;
      pkA[0] = bf16rne(sA[0]) | (bf16rne(sA[1]) << 16);
      pkA[1] = bf16rne(sA[2]) | (bf16rne(sA[3]) << 16);
      pkB[0] = bf16rne(sB[0]) | (bf16rne(sB[1]) << 16);
      pkB[1] = bf16rne(sB[2]) | (bf16rne(sB[3]) << 16);
      const int sa_in = 4 * lg;
      const int sb_in = 16 + 4 * lg;
      *(u32x2*)&p_lds[w * 2048 + sb * 512 + ((sa_in >> 3) * 16 + lh) * 8 + (sa_in & 7)] = pkA;
      *(u32x2*)&p_lds[w * 2048 + sb * 512 + ((sb_in >> 3) * 16 + lh) * 8 + (sb_in & 7)] = pkB;
    }

    asm volatile("s_waitcnt lgkmcnt(0)" ::: "memory");
    __builtin_amdgcn_sched_barrier(0);
    __builtin_amdgcn_s_barrier();      // buf (sb&1) free for restage

    if (sb == 0) stageK(2, 0);
    else if (sb == 1) stageK(3, 1);
    else if (sb == 2) stageH(0, 0);    // hides under sb=3 + PV
  }
  stageH(1, 1);

  // ---- PV: O += P * V_i (vt frags via tracked global; L2-local) ----
  for (int f = 0; f < nsb; ++f) {
    bf16x8 pa = *(const bf16x8*)&p_lds[w * 2048 + f * 512 + lane * 8];
    const unsigned short* vb = vt_h + (size_t)(ch * 4 + f) * 4096 + lane * 8;
#pragma unroll
    for (int df = 0; df < 8; ++df) {
      bf16x8 vf = *(const bf16x8*)(vb + df * 512);
      o[df] = __builtin_amdgcn_mfma_f32_16x16x32_bf16(pa, vf, o[df], 0, 0, 0);
    }
  }

  // ---- QH loop: 4 df-pair stages from overlaid LDS dbuf (H_0 = 0 exact) ----
  for (int q = 0; q < 4; ++q) {
    if (q < 3) asm volatile("s_waitcnt vmcnt(4)" ::: "memory");
    else       asm volatile("s_waitcnt vmcnt(0)" ::: "memory");
    __builtin_amdgcn_s_barrier();
    __builtin_amdgcn_sched_barrier(0);

    const unsigned short* hbuf = &kh_lds[q & 1][0];
#pragma unroll
    for (int ks = 0; ks < 16; ++ks) {
      bf16x8 qa = __builtin_bit_cast(bf16x8, qf[ks]);
      bf16x8 hf0 = *(const bf16x8*)(hbuf + ks * 1024 + lane * 8);
      bf16x8 hf1 = *(const bf16x8*)(hbuf + ks * 1024 + 512 + lane * 8);
      o[2 * q] = __builtin_amdgcn_mfma_f32_16x16x32_bf16(qa, hf0, o[2 * q], 0, 0, 0);
      o[2 * q + 1] = __builtin_amdgcn_mfma_f32_16x16x32_bf16(qa, hf1, o[2 * q + 1], 0, 0, 0);
    }

    asm volatile("s_waitcnt lgkmcnt(0)" ::: "memory");
    __builtin_amdgcn_sched_barrier(0);
    __builtin_amdgcn_s_barrier();      // half (q&1) free for restage

    if (q < 2) stageH(q + 2, q & 1);
  }

  // ---- epilogue: plain stores, each element written exactly once ----
  float* ob = out_h + (size_t)(tb + 4 * lg) * DV_DIM + lh;
#pragma unroll
  for (int df = 0; df < 8; ++df)
#pragma unroll
    for (int r = 0; r < 4; ++r)
      ob[(size_t)r * DV_DIM + df * 16] = o[df][r];
}

extern "C" void kernel_launch(void* const* d_in, const int* in_sizes, int n_in,
                              void* d_out, int out_size, void* d_ws, size_t ws_size,
                              hipStream_t stream) {
  const float* Q = (const float*)d_in[0];
  const float* V = (const float*)d_in[1];
  const float* freqs = (const float*)d_in[2];
  float* out = (float*)d_out;

  unsigned short* qr = (unsigned short*)d_ws;                 // 33.5 MB
  unsigned short* vt = qr + (size_t)16777216;                 // 8.4 MB
  unsigned short* H = vt + (size_t)4194304;                   // 33.5 MB

  hipLaunchKernelGGL(prep_kernel, dim3(5120), dim3(256), 0, stream,
                     Q, freqs, V, (unsigned int*)qr, vt);
  hipLaunchKernelGGL(hprefix_kernel, dim3(256), dim3(256), 0, stream, qr, vt, H);
  hipLaunchKernelGGL(chunk_kernel, dim3(256), dim3(512), 0, stream, qr, vt, H, out);
}

// Round 24
// 77.878 us; speedup vs baseline: 1.6149x; 1.6149x over previous
//
#include <hip/hip_runtime.h>
#include <hip/hip_bf16.h>
#include <stdint.h>

#define T_DIM 2048
#define N_DIM 512
#define DV_DIM 128
#define NH 16          // B*H

typedef __bf16 bf16x8 __attribute__((ext_vector_type(8)));
typedef float f32x4 __attribute__((ext_vector_type(4)));
typedef float f32x2 __attribute__((ext_vector_type(2)));
typedef unsigned int u32x2 __attribute__((ext_vector_type(2)));
typedef unsigned int u32x4 __attribute__((ext_vector_type(4)));

__device__ __forceinline__ unsigned bf16rne(float x) {
  unsigned u = __builtin_bit_cast(unsigned, x);
  return (u + 0x7FFFu + ((u >> 16) & 1u)) >> 16;
}

__device__ __forceinline__ void load_lds16(const void* g, void* l) {
  __builtin_amdgcn_global_load_lds((const __attribute__((address_space(1))) void*)g,
                                   (__attribute__((address_space(3))) void*)l, 16, 0, 0);
}

// ---------------- fused prep: RoPE+transpose (blocks 0..4095) and
// V frag-linear transform (blocks 4096..5119), one launch ----------------
// All outputs bh-pinned to XCD bh%8 matching consumers. This is the proven
// v20 configuration (restored after the v23 in-LDS-transpose regression).
__global__ __launch_bounds__(256, 2)
void prep_kernel(const float* __restrict__ Q, const float* __restrict__ freqs,
                 const float* __restrict__ V,
                 unsigned int* __restrict__ qrOut,
                 unsigned int* __restrict__ qrTOut,
                 unsigned short* __restrict__ vt32) {
  __shared__ unsigned int smem32[2112];      // 8448 B, union of both paths
  const int bid = blockIdx.x;
  const int tid = threadIdx.x;

  if (bid < 4096) {
    // ---- RoPE + transpose: Q fp32 [bh][t][n] -> qr bf16 + qrT bf16 ----
    auto tile32 = reinterpret_cast<unsigned int(*)[33]>(smem32);      // [64][33] u32
    const unsigned short* tile16 = reinterpret_cast<const unsigned short*>(smem32); // row stride 66
    const int k = bid >> 3;
    const int bh = (bid & 7) + 8 * (k & 1);
    const int rest = k >> 1;           // 0..255
    const int tt = rest >> 3;          // 0..31
    const int nn = rest & 7;           // 0..7
    const int t0 = tt * 64, n0 = nn * 64;

    const int c2 = tid & 31;           // n-pair, invariant across iters
    const int r0 = tid >> 5;           // 0..7
    const float f = freqs[n0 + 2 * c2];

    const float* src = Q + ((size_t)bh * T_DIM + t0) * N_DIM + n0 + 2 * c2;
    f32x2 qv[8];
#pragma unroll
    for (int it = 0; it < 8; ++it)
      qv[it] = *(const f32x2*)(src + (size_t)(it * 8 + r0) * N_DIM);

    unsigned int* qrb = qrOut + ((size_t)bh * T_DIM + t0) * 256 + (n0 >> 1) + c2;
#pragma unroll
    for (int it = 0; it < 8; ++it) {
      int r = it * 8 + r0;             // t-local
      float ph = (float)(t0 + r) * f;
      ph = ph - floorf(ph);            // revolutions in [0,1)
      float sn = __builtin_amdgcn_sinf(ph);
      float cn = __builtin_amdgcn_cosf(ph);
      unsigned lo = bf16rne(qv[it].x * cn - qv[it].y * sn);
      unsigned hi = bf16rne(qv[it].y * cn + qv[it].x * sn);
      unsigned pk = lo | (hi << 16);
      qrb[(size_t)r * 256] = pk;
      tile32[r][c2] = pk;              // aligned u32
    }
    __syncthreads();
    unsigned int* dstb = qrTOut + ((size_t)bh * N_DIM + n0) * 1024 + (t0 >> 1);
#pragma unroll
    for (int it = 0; it < 8; ++it) {
      int slot = it * 256 + tid;       // 0..2047
      int rn = slot >> 5;              // n-local 0..63
      int c2r = slot & 31;             // t-pair 0..31
      unsigned lo = tile16[(2 * c2r) * 66 + rn];
      unsigned hi = tile16[(2 * c2r + 1) * 66 + rn];
      dstb[(size_t)rn * 1024 + c2r] = lo | (hi << 16);
    }
  } else {
    // ---- V fp32 [bh][t][d] -> frag-linear bf16 (16x16x32 B-frag):
    // vt[bh][sblk32][slot=df*64+lane][i] = V[s0+8*(lane>>4)+i][16*df+(lane&15)]
    auto tile = reinterpret_cast<unsigned short(*)[128]>(smem32);
    const int vb = bid - 4096;
    const int bh = (vb & 7) + 8 * ((vb >> 3) & 1);
    const int sb = vb >> 4;            // 0..63
    const float* src = V + ((size_t)bh * T_DIM + sb * 32) * DV_DIM;
    f32x4 vv[4];
#pragma unroll
    for (int i = 0; i < 4; ++i)
      vv[i] = *(const f32x4*)(src + (size_t)(i * 1024 + tid * 4));
#pragma unroll
    for (int i = 0; i < 4; ++i) {
      int idx4 = i * 256 + tid;        // vec4-slot over [32][128]
      int row = idx4 >> 5;
      int col4 = idx4 & 31;
      u32x2 pk;
      pk[0] = bf16rne(vv[i][0]) | (bf16rne(vv[i][1]) << 16);
      pk[1] = bf16rne(vv[i][2]) | (bf16rne(vv[i][3]) << 16);
      *(u32x2*)&tile[row][col4 * 4] = pk;
    }
    __syncthreads();
    unsigned short* dst = vt32 + ((size_t)bh * 64 + sb) * 4096;
#pragma unroll
    for (int jj = 0; jj < 2; ++jj) {
      int j = jj * 256 + tid;
      int df = j >> 6, ln = j & 63;
      int lh2 = ln & 15, lg2 = ln >> 4;
      unsigned short tmp[8];
#pragma unroll
      for (int i = 0; i < 8; ++i) tmp[i] = tile[8 * lg2 + i][16 * df + lh2];
      *(u32x4*)(dst + j * 8) = *(u32x4*)tmp;
    }
  }
}

// ---------------- fused G + exclusive prefix -> H (v18-proven) ----------------
// H[t] = sum_{chunks k < i} QR_k^T V_k, emitted bf16 B-frag-linear.
__global__ __launch_bounds__(256, 1)
void hprefix_kernel(const unsigned short* __restrict__ qrT,
                    const unsigned short* __restrict__ vt,
                    unsigned short* __restrict__ H) {
  const int bid = blockIdx.x;
  const int bh = (bid & 7) + 8 * ((bid >> 3) & 1);
  const int slab = bid >> 4;           // 0..15
  const int nsl = slab >> 2;
  const int dsl = slab & 3;
  const int tid = threadIdx.x;
  const int w = tid >> 6;
  const int lane = tid & 63;
  const int lh = lane & 15, lg = lane >> 4;

  const unsigned short* qrT_h = qrT + (size_t)bh * (N_DIM * T_DIM);
  const unsigned short* vt_h = vt + (size_t)bh * (64 * 4096);
  unsigned short* H_h = H + (size_t)bh * (16 * 65536);

  const f32x4 fzero = {0.f, 0.f, 0.f, 0.f};
  f32x4 acc00 = fzero, acc01 = fzero, acc10 = fzero, acc11 = fzero;

  for (int ch = 0; ch < 16; ++ch) {
    // ---- emit H_ch = prefix so far (exclusive) ----
#pragma unroll
    for (int nf = 0; nf < 2; ++nf)
#pragma unroll
      for (int dfl = 0; dfl < 2; ++dfl) {
        const f32x4 a = (nf == 0) ? (dfl == 0 ? acc00 : acc01)
                                  : (dfl == 0 ? acc10 : acc11);
        int nloc = w * 32 + nf * 16 + 4 * lg;
        int nblk = nsl * 4 + (nloc >> 5);
        int lg2 = (nloc >> 3) & 3;
        int i0 = nloc & 7;
        int df = dsl * 2 + dfl;
        int slot = df * 64 + lg2 * 16 + lh;
        u32x2 pk;
        pk[0] = bf16rne(a[0]) | (bf16rne(a[1]) << 16);
        pk[1] = bf16rne(a[2]) | (bf16rne(a[3]) << 16);
        *(u32x2*)(H_h + (size_t)ch * 65536 + nblk * 4096 + slot * 8 + i0) = pk;
      }
    // ---- accumulate G_ch ----
#pragma unroll
    for (int ks = 0; ks < 4; ++ks) {
      u32x4 a0, a1, b0, b1;
      {
        const unsigned short* pa = qrT_h + (size_t)(nsl * 128 + w * 32 + lh) * T_DIM
                                   + ch * 128 + ks * 32 + lg * 8;
        a0 = *(const u32x4*)pa;
        a1 = *(const u32x4*)(pa + 16 * T_DIM);
        const unsigned short* pb = vt_h + (size_t)(ch * 4 + ks) * 4096
                                   + ((dsl * 2) * 64 + lane) * 8;
        b0 = *(const u32x4*)pb;
        b1 = *(const u32x4*)(pb + 512);
      }
      acc00 = __builtin_amdgcn_mfma_f32_16x16x32_bf16(__builtin_bit_cast(bf16x8, a0), __builtin_bit_cast(bf16x8, b0), acc00, 0, 0, 0);
      acc01 = __builtin_amdgcn_mfma_f32_16x16x32_bf16(__builtin_bit_cast(bf16x8, a0), __builtin_bit_cast(bf16x8, b1), acc01, 0, 0, 0);
      acc10 = __builtin_amdgcn_mfma_f32_16x16x32_bf16(__builtin_bit_cast(bf16x8, a1), __builtin_bit_cast(bf16x8, b0), acc10, 0, 0, 0);
      acc11 = __builtin_amdgcn_mfma_f32_16x16x32_bf16(__builtin_bit_cast(bf16x8, a1), __builtin_bit_cast(bf16x8, b1), acc11, 0, 0, 0);
    }
  }
}

// ---------------- per-chunk output: O = QR_i H_i + tril(QR_i QR_i^T,-1) V_i ----------------
// 256 wgs = (head pinned to XCD, ch) x 512 thr (8 waves; wave w owns 16
// t-rows, ALL 8 d-frags). K staged read-once via 2x32KB LDS dbuf (counted
// vmcnt(4) + raw barriers); the same 64KB then serves as the H dbuf for 4
// df-pair stages (overlay; H read-once). 96KB LDS -> 1 wg/CU.
__global__ __launch_bounds__(512, 1)
void chunk_kernel(const unsigned short* __restrict__ qr,
                  const unsigned short* __restrict__ vt,
                  const unsigned short* __restrict__ H,
                  float* __restrict__ out) {
  __shared__ unsigned short kh_lds[2][16384];  // 2x32KB: K dbuf, then H dbuf
  __shared__ unsigned short p_lds[8 * 2048];   // 32KB: [wave][sb 4][A-frag 512]

  const int tid = threadIdx.x;
  const int w = tid >> 6;              // 0..7
  const int lane = tid & 63;
  const int lh = lane & 15, lg = lane >> 4;

  const int bid = blockIdx.x;          // 256 wgs
  const int head = (bid & 7) + 8 * ((bid >> 3) & 1);
  const int ch = bid >> 4;             // 0..15

  const unsigned short* qr_h = qr + (size_t)head * (T_DIM * N_DIM);
  const unsigned short* vt_h = vt + (size_t)head * (64 * 4096);
  const unsigned short* H_c = H + ((size_t)head * 16 + ch) * 65536;
  float* out_h = out + (size_t)head * (T_DIM * DV_DIM);

  const int tq = w * 16;               // t local to chunk
  const int tb = ch * 128 + tq;
  const int nsb = (w >> 1) + 1;        // causal 32-s blocks for this wave

  // ---- Q fragments first (tracked): row = t = tb+lh, k = 32ks+8lg+i ----
  u32x4 qf[16];
  {
    const unsigned short* pq = qr_h + (size_t)(tb + lh) * N_DIM + lg * 8;
#pragma unroll
    for (int ks = 0; ks < 16; ++ks) qf[ks] = *(const u32x4*)(pq + ks * 32);
  }

  // K stage: 32-row block sb -> A-frag-linear [f=st*16+ks][lane*8], 32KB
  int koff[4];
#pragma unroll
  for (int it = 0; it < 4; ++it) {
    int j = it * 512 + tid;            // slot 0..2047
    int f = j >> 6, l = j & 63;
    int st = f >> 4, ks = f & 15;
    koff[it] = (st * 16 + (l & 15)) * 1024 + ks * 64 + (l >> 4) * 16;
  }
  auto stageK = [&](int sb, int buf) {
    const char* kb = (const char*)qr_h + ((size_t)ch * 128 + sb * 32) * 1024;
#pragma unroll
    for (int it = 0; it < 4; ++it)
      load_lds16(kb + koff[it], (char*)&kh_lds[buf][0] + (it * 512 + tid) * 16);
  };
  // H stage q (df-pair 2q,2q+1): [nb 16][dfp 2][lane][8] = 32KB
  auto stageH = [&](int q, int buf) {
#pragma unroll
    for (int it = 0; it < 4; ++it) {
      int s = it * 512 + tid;          // slot 0..2047
      int nb = s >> 7;
      int dfp = (s >> 6) & 1;
      int l = s & 63;
      const unsigned short* src = H_c + nb * 4096 + (2 * q + dfp) * 512 + l * 8;
      load_lds16(src, (char*)&kh_lds[buf][0] + s * 16);
    }
  };

  stageK(0, 0);
  stageK(1, 1);

  const f32x4 fzero = {0.f, 0.f, 0.f, 0.f};
  f32x4 o[8];
#pragma unroll
  for (int df = 0; df < 8; ++df) o[df] = fzero;

  // ---- QK loop: 4 staged iterations, counted vmcnt, uniform barriers ----
  for (int sb = 0; sb < 4; ++sb) {
    asm volatile("s_waitcnt vmcnt(4)" ::: "memory");  // K(sb) landed
    __builtin_amdgcn_s_barrier();
    __builtin_amdgcn_sched_barrier(0);

    if (sb < nsb) {
      f32x4 sA = fzero, sB = fzero;
      const unsigned short* kbuf = &kh_lds[sb & 1][0];
#pragma unroll
      for (int ks = 0; ks < 16; ++ks) {
        bf16x8 kf0 = *(const bf16x8*)(kbuf + ks * 512 + lane * 8);
        bf16x8 kf1 = *(const bf16x8*)(kbuf + (16 + ks) * 512 + lane * 8);
        bf16x8 qb = __builtin_bit_cast(bf16x8, qf[ks]);
        sA = __builtin_amdgcn_mfma_f32_16x16x32_bf16(kf0, qb, sA, 0, 0, 0);
        sB = __builtin_amdgcn_mfma_f32_16x16x32_bf16(kf1, qb, sB, 0, 0, 0);
      }
      const int tloc = tq + lh;
#pragma unroll
      for (int r = 0; r < 4; ++r) {
        if (sb * 32 + 4 * lg + r >= tloc) sA[r] = 0.f;
        if (sb * 32 + 16 + 4 * lg + r >= tloc) sB[r] = 0.f;
      }
      u32x2 pkA, pkB;
      pkA[0] = bf16rne(sA[0]) | (bf16rne(sA[1]) << 16);
      pkA[1] = bf16rne(sA[2]) | (bf16rne(sA[3]) << 16);
      pkB[0] = bf16rne(sB[0]) | (bf16rne(sB[1]) << 16);
      pkB[1] = bf16rne(sB[2]) | (bf16rne(sB[3]) << 16);
      const int sa_in = 4 * lg;
      const int sb_in = 16 + 4 * lg;
      *(u32x2*)&p_lds[w * 2048 + sb * 512 + ((sa_in >> 3) * 16 + lh) * 8 + (sa_in & 7)] = pkA;
      *(u32x2*)&p_lds[w * 2048 + sb * 512 + ((sb_in >> 3) * 16 + lh) * 8 + (sb_in & 7)] = pkB;
    }

    asm volatile("s_waitcnt lgkmcnt(0)" ::: "memory");
    __builtin_amdgcn_sched_barrier(0);
    __builtin_amdgcn_s_barrier();      // buf (sb&1) free for restage

    if (sb == 0) stageK(2, 0);
    else if (sb == 1) stageK(3, 1);
    else if (sb == 2) stageH(0, 0);    // hides under sb=3 + PV
  }
  stageH(1, 1);

  // ---- PV: O += P * V_i (vt frags via tracked global; L2-local) ----
  for (int f = 0; f < nsb; ++f) {
    bf16x8 pa = *(const bf16x8*)&p_lds[w * 2048 + f * 512 + lane * 8];
    const unsigned short* vb = vt_h + (size_t)(ch * 4 + f) * 4096 + lane * 8;
#pragma unroll
    for (int df = 0; df < 8; ++df) {
      bf16x8 vf = *(const bf16x8*)(vb + df * 512);
      o[df] = __builtin_amdgcn_mfma_f32_16x16x32_bf16(pa, vf, o[df], 0, 0, 0);
    }
  }

  // ---- QH loop: 4 df-pair stages from overlaid LDS dbuf (H_0 = 0 exact) ----
  for (int q = 0; q < 4; ++q) {
    if (q < 3) asm volatile("s_waitcnt vmcnt(4)" ::: "memory");
    else       asm volatile("s_waitcnt vmcnt(0)" ::: "memory");
    __builtin_amdgcn_s_barrier();
    __builtin_amdgcn_sched_barrier(0);

    const unsigned short* hbuf = &kh_lds[q & 1][0];
#pragma unroll
    for (int ks = 0; ks < 16; ++ks) {
      bf16x8 qa = __builtin_bit_cast(bf16x8, qf[ks]);
      bf16x8 hf0 = *(const bf16x8*)(hbuf + ks * 1024 + lane * 8);
      bf16x8 hf1 = *(const bf16x8*)(hbuf + ks * 1024 + 512 + lane * 8);
      o[2 * q] = __builtin_amdgcn_mfma_f32_16x16x32_bf16(qa, hf0, o[2 * q], 0, 0, 0);
      o[2 * q + 1] = __builtin_amdgcn_mfma_f32_16x16x32_bf16(qa, hf1, o[2 * q + 1], 0, 0, 0);
    }

    asm volatile("s_waitcnt lgkmcnt(0)" ::: "memory");
    __builtin_amdgcn_sched_barrier(0);
    __builtin_amdgcn_s_barrier();      // half (q&1) free for restage

    if (q < 2) stageH(q + 2, q & 1);
  }

  // ---- epilogue: plain stores, each element written exactly once ----
  float* ob = out_h + (size_t)(tb + 4 * lg) * DV_DIM + lh;
#pragma unroll
  for (int df = 0; df < 8; ++df)
#pragma unroll
    for (int r = 0; r < 4; ++r)
      ob[(size_t)r * DV_DIM + df * 16] = o[df][r];
}

extern "C" void kernel_launch(void* const* d_in, const int* in_sizes, int n_in,
                              void* d_out, int out_size, void* d_ws, size_t ws_size,
                              hipStream_t stream) {
  const float* Q = (const float*)d_in[0];
  const float* V = (const float*)d_in[1];
  const float* freqs = (const float*)d_in[2];
  float* out = (float*)d_out;

  unsigned short* qr = (unsigned short*)d_ws;                 // 33.5 MB
  unsigned short* qrT = qr + (size_t)16777216;                // 33.5 MB
  unsigned short* vt = qrT + (size_t)16777216;                // 8.4 MB
  unsigned short* H = vt + (size_t)4194304;                   // 33.5 MB

  hipLaunchKernelGGL(prep_kernel, dim3(5120), dim3(256), 0, stream,
                     Q, freqs, V, (unsigned int*)qr, (unsigned int*)qrT, vt);
  hipLaunchKernelGGL(hprefix_kernel, dim3(256), dim3(256), 0, stream, qrT, vt, H);
  hipLaunchKernelGGL(chunk_kernel, dim3(256), dim3(512), 0, stream, qr, vt, H, out);
}